// Round 1
// baseline (47.170 us; speedup 1.0000x reference)
//
#include <hip/hip_runtime.h>

// ALS gather-dot: out[b] = dot(user[loc[b,0], :], goods[:, loc[b,1]])
// user: [500000, 128] f32 row-major   -> row gather, contiguous
// goods: [128, 500000] f32 row-major  -> column gather, stride 500000
// location: [16384, 2] int            -> out: [16384] f32

#define KDIM 128
#define GOODS_NUM 500000

__global__ __launch_bounds__(256) void als_gather_dot(
    const float* __restrict__ user,
    const float* __restrict__ goods,
    const int* __restrict__ loc,
    float* __restrict__ out,
    int batch)
{
    const int gtid = blockIdx.x * blockDim.x + threadIdx.x;
    const int wave = gtid >> 6;          // one wave64 per output element
    const int lane = threadIdx.x & 63;
    if (wave >= batch) return;

    const int urow = loc[wave * 2 + 0];
    const int gcol = loc[wave * 2 + 1];

    // u row: contiguous 128 floats; lane i takes elements 2i, 2i+1 (coalesced float2)
    const float2 uv = *reinterpret_cast<const float2*>(
        user + (size_t)urow * KDIM + (size_t)(lane * 2));

    // g column: stride GOODS_NUM floats (2 MB) -> inherently scattered
    const float g0 = goods[(size_t)(lane * 2)     * GOODS_NUM + (size_t)gcol];
    const float g1 = goods[(size_t)(lane * 2 + 1) * GOODS_NUM + (size_t)gcol];

    float s = uv.x * g0 + uv.y * g1;

    // wave64 butterfly reduction
    #pragma unroll
    for (int off = 32; off >= 1; off >>= 1)
        s += __shfl_xor(s, off, 64);

    if (lane == 0) out[wave] = s;
}

extern "C" void kernel_launch(void* const* d_in, const int* in_sizes, int n_in,
                              void* d_out, int out_size, void* d_ws, size_t ws_size,
                              hipStream_t stream)
{
    const float* user  = (const float*)d_in[0];
    const float* goods = (const float*)d_in[1];
    const int*   loc   = (const int*)d_in[2];
    float* out = (float*)d_out;

    const int batch = out_size;                 // 16384 outputs
    const int threads = 256;                    // 4 waves/block
    const int blocks = (batch * 64 + threads - 1) / threads;
    als_gather_dot<<<blocks, threads, 0, stream>>>(user, goods, loc, out, batch);
}